// Round 2
// baseline (618.159 us; speedup 1.0000x reference)
//
#include <hip/hip_runtime.h>

typedef unsigned short u16;
typedef unsigned int   u32;

#define NB   32
#define CIN  512
#define CM   128
#define P2   256
#define HW   3136
#define HD   56

typedef __attribute__((ext_vector_type(8))) short           short8;
typedef __attribute__((ext_vector_type(8))) unsigned short  ushort8;
typedef __attribute__((ext_vector_type(4))) unsigned short  ushort4_t;
typedef __attribute__((ext_vector_type(4))) float           f32x4;

__device__ __forceinline__ float b2f(u16 u) {
    union { u32 i; float f; } v; v.i = ((u32)u) << 16; return v.f;
}
__device__ __forceinline__ u16 f2b(float f) {
    u32 u = __builtin_bit_cast(u32, f);
    u32 r = (u + 0x7fffu + ((u >> 16) & 1u)) >> 16;
    return (u16)r;
}

// ---------------- kernel 0: convert weights f32 -> bf16 ----------------
__global__ __launch_bounds__(256) void cvt_kernel(const float* __restrict__ Wc,
                                                  const float* __restrict__ Wf,
                                                  u16* __restrict__ Wcb,
                                                  u16* __restrict__ Wfb) {
    int i = blockIdx.x * 256 + threadIdx.x;
    if (i < CM * CIN) Wcb[i] = f2b(Wc[i]);
    else {
        int j = i - CM * CIN;
        if (j < P2 * CM) Wfb[j] = f2b(Wf[j]);
    }
}

// ---------------- kernel 1: xm[n,c] = mean_hw x[n,c,:] ----------------
__global__ __launch_bounds__(256) void mean_kernel(const float* __restrict__ x,
                                                   float* __restrict__ xm) {
    const int nc = blockIdx.x;
    const f32x4* p = (const f32x4*)(x + (size_t)nc * HW);
    float s = 0.f;
    for (int i = threadIdx.x; i < HW / 4; i += 256) {
        f32x4 v = p[i];
        s += v[0] + v[1] + v[2] + v[3];
    }
    for (int off = 32; off > 0; off >>= 1) s += __shfl_down(s, off);
    __shared__ float red[4];
    const int wave = threadIdx.x >> 6, lane = threadIdx.x & 63;
    if (lane == 0) red[wave] = s;
    __syncthreads();
    if (threadIdx.x == 0)
        xm[nc] = (red[0] + red[1] + red[2] + red[3]) * (1.0f / HW);
}

// ---------------- kernel 2: g[n,cm] = relu(W_conv . xm + b) ----------------
__global__ __launch_bounds__(128) void g_kernel(const float* __restrict__ Wc,
                                                const float* __restrict__ bc,
                                                const float* __restrict__ xm,
                                                float* __restrict__ g) {
    const int n = blockIdx.x, cm = threadIdx.x;
    __shared__ float xs[CIN];
    for (int i = threadIdx.x; i < CIN; i += 128) xs[i] = xm[n * CIN + i];
    __syncthreads();
    const float* wrow = Wc + (size_t)cm * CIN;
    float acc = 0.f;
    for (int c = 0; c < CIN; ++c) acc += wrow[c] * xs[c];
    acc += bc[cm];
    g[n * CM + cm] = fmaxf(acc, 0.f);
}

// ---------------- generic per-n MFMA GEMM ----------------
// Out[(n*ch_stride + ch_off + m)*HW + hw] = (relu?)(sum_k W[m][k]*In[n][k][hw] + bias[m])
// block = 256 thr (4 waves), tile 128(m) x 128(hw), K-step 32, mfma 16x16x32 bf16.
// In: f32 (in_f32=1) or bf16; Out: f32 (out_f32=1) or bf16.
__global__ __launch_bounds__(256) void gemm_kernel(
    const void* __restrict__ In, int in_f32,
    const u16* __restrict__ Wm, const float* __restrict__ bias,
    void* __restrict__ Out, int out_f32,
    int K, int ch_stride, int ch_off, int do_relu)
{
    __shared__ u16 ldsT[128 * 36];   // [hw_col][k] transposed, stride 36 (pad 4)

    const int n    = blockIdx.z;
    const int hw0  = blockIdx.x * 128;
    const int mblk = blockIdx.y * 128;
    const int tid  = threadIdx.x;
    const int wave = tid >> 6, lane = tid & 63;
    const int wm   = (wave >> 1) * 64;   // wave m-offset
    const int wn   = (wave & 1) * 64;    // wave hw-offset
    const int qa   = lane >> 4;          // k-quad 0..3
    const int l15  = lane & 15;

    f32x4 acc[4][4] = {};

    // staging assignment: thread -> 2 k-rows x 8 hw-cols
    const int kpair = tid >> 4;            // 0..15 -> k rows 2*kpair, 2*kpair+1
    const int c0    = (tid & 15) * 8;      // hw col group
    const int hwc   = hw0 + c0;
    const bool cok  = (hwc < HW);

    for (int k0 = 0; k0 < K; k0 += 32) {
        __syncthreads();
        u32 pk[8];
        if (in_f32) {
            f32x4 a0 = {0,0,0,0}, a1 = {0,0,0,0}, d0 = {0,0,0,0}, d1 = {0,0,0,0};
            if (cok) {
                const float* p0 = (const float*)In + (size_t)n * K * HW
                                + (size_t)(k0 + kpair * 2) * HW + hwc;
                a0 = *(const f32x4*)p0;
                a1 = *(const f32x4*)(p0 + 4);
                d0 = *(const f32x4*)(p0 + HW);
                d1 = *(const f32x4*)(p0 + HW + 4);
            }
            float ra[8] = {a0[0],a0[1],a0[2],a0[3],a1[0],a1[1],a1[2],a1[3]};
            float rb[8] = {d0[0],d0[1],d0[2],d0[3],d1[0],d1[1],d1[2],d1[3]};
            #pragma unroll
            for (int e = 0; e < 8; ++e)
                pk[e] = (u32)f2b(ra[e]) | ((u32)f2b(rb[e]) << 16);
        } else {
            ushort8 v0 = {0,0,0,0,0,0,0,0}, v1 = {0,0,0,0,0,0,0,0};
            if (cok) {
                const u16* p0 = (const u16*)In + (size_t)n * K * HW
                              + (size_t)(k0 + kpair * 2) * HW + hwc;
                v0 = *(const ushort8*)p0;
                v1 = *(const ushort8*)(p0 + HW);
            }
            #pragma unroll
            for (int e = 0; e < 8; ++e)
                pk[e] = (u32)v0[e] | ((u32)v1[e] << 16);
        }
        #pragma unroll
        for (int e = 0; e < 8; ++e)
            *(u32*)&ldsT[(c0 + e) * 36 + kpair * 2] = pk[e];
        __syncthreads();

        short8 a[4];
        #pragma unroll
        for (int mt = 0; mt < 4; ++mt) {
            int row = mblk + wm + mt * 16 + l15;
            a[mt] = *(const short8*)(Wm + (size_t)row * K + k0 + qa * 8);
        }
        #pragma unroll
        for (int nt = 0; nt < 4; ++nt) {
            int c = wn + nt * 16 + l15;
            union { ushort4_t h[2]; short8 v; } bu;
            bu.h[0] = *(const ushort4_t*)&ldsT[c * 36 + qa * 8];
            bu.h[1] = *(const ushort4_t*)&ldsT[c * 36 + qa * 8 + 4];
            short8 b = bu.v;
            #pragma unroll
            for (int mt = 0; mt < 4; ++mt)
                acc[mt][nt] = __builtin_amdgcn_mfma_f32_16x16x32_bf16(a[mt], b, acc[mt][nt], 0, 0, 0);
        }
    }

    // epilogue: C/D layout col=lane&15, row=(lane>>4)*4+reg
    const int r4 = qa * 4;
    #pragma unroll
    for (int nt = 0; nt < 4; ++nt) {
        int colhw = hw0 + wn + nt * 16 + l15;
        if (colhw >= HW) continue;
        #pragma unroll
        for (int mt = 0; mt < 4; ++mt) {
            int mbase = mblk + wm + mt * 16 + r4;
            #pragma unroll
            for (int r = 0; r < 4; ++r) {
                int m = mbase + r;
                float v = acc[mt][nt][r] + bias[m];
                if (do_relu) v = fmaxf(v, 0.f);
                size_t idx = ((size_t)n * ch_stride + ch_off + m) * HW + colhw;
                if (out_f32) ((float*)Out)[idx] = v;
                else         ((u16*)Out)[idx]  = f2b(v);
            }
        }
    }
}

// ---------------- kernel 4: both depthwise branches ----------------
// o1 = dwconv5x5(f, kern1(g)), o2 = dwconv3x3_dil2(f, kern2(g)); block per (n,cm)
__global__ __launch_bounds__(256) void dw_kernel(
    const u16* __restrict__ f, const float* __restrict__ g,
    const float* __restrict__ wk,  const float* __restrict__ bk,
    const float* __restrict__ wck, const float* __restrict__ bck,
    const float* __restrict__ wk2, const float* __restrict__ bk2,
    const float* __restrict__ wck2,const float* __restrict__ bck2,
    u16* __restrict__ o1, u16* __restrict__ o2)
{
    const int ncm = blockIdx.x;
    __shared__ float fpl[HW];
    __shared__ float kc1[25], kc2[9];

    const u16* fp = f + (size_t)ncm * HW;
    for (int i = threadIdx.x; i < HW; i += 256) fpl[i] = b2f(fp[i]);

    const float gv = g[ncm];
    if (threadIdx.x < 25) {
        int t = threadIdx.x;
        kc1[t] = (gv * wk[t] + bk[t]) * wck[0] + bck[0];
    } else if (threadIdx.x >= 32 && threadIdx.x < 41) {
        int t = threadIdx.x - 32;
        kc2[t] = (gv * wk2[t] + bk2[t]) * wck2[0] + bck2[0];
    }
    __syncthreads();

    const size_t base = (size_t)ncm * HW;
    for (int px = threadIdx.x; px < HW; px += 256) {
        int h = px / HD, w = px - h * HD;
        float a1 = 0.f;
        #pragma unroll
        for (int i = 0; i < 5; ++i) {
            int hh = h + i - 2; if (hh < 0 || hh >= HD) continue;
            #pragma unroll
            for (int j = 0; j < 5; ++j) {
                int ww = w + j - 2; if (ww < 0 || ww >= HD) continue;
                a1 += kc1[i * 5 + j] * fpl[hh * HD + ww];
            }
        }
        float a2 = 0.f;
        #pragma unroll
        for (int i = 0; i < 3; ++i) {
            int hh = h + (i - 1) * 2; if (hh < 0 || hh >= HD) continue;
            #pragma unroll
            for (int j = 0; j < 3; ++j) {
                int ww = w + (j - 1) * 2; if (ww < 0 || ww >= HD) continue;
                a2 += kc2[i * 3 + j] * fpl[hh * HD + ww];
            }
        }
        o1[base + px] = f2b(a1);
        o2[base + px] = f2b(a2);
    }
}

extern "C" void kernel_launch(void* const* d_in, const int* in_sizes, int n_in,
                              void* d_out, int out_size, void* d_ws, size_t ws_size,
                              hipStream_t stream) {
    const float* x     = (const float*)d_in[0];
    const float* Wconv = (const float*)d_in[1];
    const float* bconv = (const float*)d_in[2];
    const float* wk    = (const float*)d_in[3];
    const float* bk    = (const float*)d_in[4];
    const float* wck   = (const float*)d_in[5];
    const float* bck   = (const float*)d_in[6];
    const float* wk2   = (const float*)d_in[7];
    const float* bk2   = (const float*)d_in[8];
    const float* wck2  = (const float*)d_in[9];
    const float* bck2  = (const float*)d_in[10];
    const float* Wfuse = (const float*)d_in[11];
    const float* bfuse = (const float*)d_in[12];
    float* out = (float*)d_out;

    // workspace layout (all regions fully rewritten every call)
    float* xm  = (float*)d_ws;                // NB*CIN f32
    float* g   = xm + NB * CIN;               // NB*CM f32
    u16*   Wcb = (u16*)(g + NB * CM);         // CM*CIN bf16
    u16*   Wfb = Wcb + CM * CIN;              // P2*CM bf16
    u16*   f   = Wfb + P2 * CM;               // NB*CM*HW bf16
    u16*   o1  = f  + (size_t)NB * CM * HW;   // NB*CM*HW bf16
    u16*   o2  = o1 + (size_t)NB * CM * HW;   // NB*CM*HW bf16

    cvt_kernel<<<dim3((CM * CIN + P2 * CM) / 256), 256, 0, stream>>>(Wconv, Wfuse, Wcb, Wfb);
    mean_kernel<<<dim3(NB * CIN), 256, 0, stream>>>(x, xm);
    g_kernel<<<dim3(NB), 128, 0, stream>>>(Wconv, bconv, xm, g);
    // f = relu(W_conv @ x)  : M=128, K=512
    gemm_kernel<<<dim3(25, 1, NB), 256, 0, stream>>>(x, 1, Wcb, bconv, f, 0, CIN, CM, 0, 1);
    dw_kernel<<<dim3(NB * CM), 256, 0, stream>>>(f, g, wk, bk, wck, bck,
                                                 wk2, bk2, wck2, bck2, o1, o2);
    // y1/y2 = W_fuse @ o1/o2 + b_fuse : M=256, K=128, into out ch 0..255 / 256..511
    gemm_kernel<<<dim3(25, 2, NB), 256, 0, stream>>>(o1, 0, Wfb, bfuse, out, 1, CM, 512, 0,  0);
    gemm_kernel<<<dim3(25, 2, NB), 256, 0, stream>>>(o2, 0, Wfb, bfuse, out, 1, CM, 512, P2, 0);
}

// Round 3
// 497.949 us; speedup vs baseline: 1.2414x; 1.2414x over previous
//
#include <hip/hip_runtime.h>

typedef unsigned short u16;
typedef unsigned int   u32;

#define NB   32
#define CIN  512
#define CM   128
#define P2   256
#define HW   3136
#define HD   56

typedef __attribute__((ext_vector_type(8))) short           short8;
typedef __attribute__((ext_vector_type(8))) unsigned short  ushort8;
typedef __attribute__((ext_vector_type(4))) unsigned short  ushort4_t;
typedef __attribute__((ext_vector_type(4))) float           f32x4;

__device__ __forceinline__ float b2f(u16 u) {
    union { u32 i; float f; } v; v.i = ((u32)u) << 16; return v.f;
}
__device__ __forceinline__ u16 f2b(float f) {
    u32 u = __builtin_bit_cast(u32, f);
    u32 r = (u + 0x7fffu + ((u >> 16) & 1u)) >> 16;
    return (u16)r;
}

// ---------------- kernel 0: zero xm + convert weights f32 -> bf16 ----------------
__global__ __launch_bounds__(256) void init_kernel(const float* __restrict__ Wc,
                                                   const float* __restrict__ Wf,
                                                   u16* __restrict__ Wcb,
                                                   u16* __restrict__ Wfb,
                                                   float* __restrict__ xm) {
    int i = blockIdx.x * 256 + threadIdx.x;
    if (i < CM * CIN) { Wcb[i] = f2b(Wc[i]); return; }
    i -= CM * CIN;
    if (i < P2 * CM) { Wfb[i] = f2b(Wf[i]); return; }
    i -= P2 * CM;
    if (i < NB * CIN) xm[i] = 0.f;
}

// ---------------- kernel 2: g[n,cm] = relu(W_conv . mean + b) ----------------
__global__ __launch_bounds__(128) void g_kernel(const float* __restrict__ Wc,
                                                const float* __restrict__ bc,
                                                const float* __restrict__ xm,
                                                float* __restrict__ g) {
    const int n = blockIdx.x, cm = threadIdx.x;
    __shared__ float xs[CIN];
    for (int i = threadIdx.x; i < CIN; i += 128)
        xs[i] = xm[n * CIN + i] * (1.0f / HW);
    __syncthreads();
    const float* wrow = Wc + (size_t)cm * CIN;
    float acc = 0.f;
    for (int c = 0; c < CIN; ++c) acc += wrow[c] * xs[c];
    acc += bc[cm];
    g[n * CM + cm] = fmaxf(acc, 0.f);
}

// ---------------- generic per-n MFMA GEMM ----------------
// Out[(n*ch_stride + ch_off + m)*HW + hw] = (relu?)(sum_k W[m][k]*In[n][k][hw] + bias[m])
// block 256 thr (4 waves), tile 128(m) x 128(hw), K-step 32, mfma 16x16x32 bf16.
// IN_F32: input f32 (converted on the fly via +0x8000 round + v_perm pack).
// MEAN:   also accumulate sum_hw In[n][k][:] into xm via 16-lane reduce + atomicAdd.
// TWOBR:  blockIdx.z encodes (n, branch); branch selects In0/In1 and ch_off 0/P2.
template<int IN_F32, int OUT_F32, int RELU, int MEAN, int TWOBR>
__global__ __launch_bounds__(256) void gemm_kernel(
    const void* __restrict__ In0, const void* __restrict__ In1,
    const u16* __restrict__ Wm, const float* __restrict__ bias,
    void* __restrict__ Out, float* __restrict__ xm,
    int K, int ch_stride)
{
    __shared__ u16 ldsT[128 * 36];   // [hw_col][k] transposed, stride 36 (pad 4)

    int n, ch_off;
    const void* In;
    if (TWOBR) {
        n      = blockIdx.z >> 1;
        int br = blockIdx.z & 1;
        In     = br ? In1 : In0;
        ch_off = br ? P2 : 0;
    } else {
        n = blockIdx.z; In = In0; ch_off = 0;
    }
    const int hw0  = blockIdx.x * 128;
    const int mblk = blockIdx.y * 128;
    const int tid  = threadIdx.x;
    const int wave = tid >> 6, lane = tid & 63;
    const int wm   = (wave >> 1) * 64;   // wave m-offset
    const int wn   = (wave & 1) * 64;    // wave hw-offset
    const int qa   = lane >> 4;          // k-quad 0..3
    const int l15  = lane & 15;

    f32x4 acc[4][4] = {};

    // staging assignment: thread -> 2 k-rows x 8 hw-cols
    const int kpair = tid >> 4;            // 0..15 -> k rows 2*kpair, 2*kpair+1
    const int c0    = (tid & 15) * 8;      // hw col group
    const int hwc   = hw0 + c0;
    const bool cok  = (hwc < HW);

    for (int k0 = 0; k0 < K; k0 += 32) {
        __syncthreads();
        u32 pk[8];
        if (IN_F32) {
            f32x4 a0 = {0,0,0,0}, a1 = {0,0,0,0}, d0 = {0,0,0,0}, d1 = {0,0,0,0};
            if (cok) {
                const float* p0 = (const float*)In + (size_t)n * K * HW
                                + (size_t)(k0 + kpair * 2) * HW + hwc;
                a0 = *(const f32x4*)p0;
                a1 = *(const f32x4*)(p0 + 4);
                d0 = *(const f32x4*)(p0 + HW);
                d1 = *(const f32x4*)(p0 + HW + 4);
            }
            float fa[8] = {a0[0],a0[1],a0[2],a0[3],a1[0],a1[1],a1[2],a1[3]};
            float fb[8] = {d0[0],d0[1],d0[2],d0[3],d1[0],d1[1],d1[2],d1[3]};
            #pragma unroll
            for (int e = 0; e < 8; ++e) {
                u32 ua = __builtin_bit_cast(u32, fa[e]) + 0x8000u;
                u32 ub = __builtin_bit_cast(u32, fb[e]) + 0x8000u;
                pk[e] = __builtin_amdgcn_perm(ub, ua, 0x07060302u);  // (hi16(ub)<<16)|hi16(ua)
            }
            if (MEAN) {
                float s0 = fa[0]+fa[1]+fa[2]+fa[3]+fa[4]+fa[5]+fa[6]+fa[7];
                float s1 = fb[0]+fb[1]+fb[2]+fb[3]+fb[4]+fb[5]+fb[6]+fb[7];
                #pragma unroll
                for (int off = 8; off > 0; off >>= 1) {
                    s0 += __shfl_xor(s0, off, 16);
                    s1 += __shfl_xor(s1, off, 16);
                }
                if ((tid & 15) == 0) {
                    atomicAdd(&xm[n * CIN + k0 + kpair * 2],     s0);
                    atomicAdd(&xm[n * CIN + k0 + kpair * 2 + 1], s1);
                }
            }
        } else {
            ushort8 v0 = {0,0,0,0,0,0,0,0}, v1 = {0,0,0,0,0,0,0,0};
            if (cok) {
                const u16* p0 = (const u16*)In + (size_t)n * K * HW
                              + (size_t)(k0 + kpair * 2) * HW + hwc;
                v0 = *(const ushort8*)p0;
                v1 = *(const ushort8*)(p0 + HW);
            }
            #pragma unroll
            for (int e = 0; e < 8; ++e)
                pk[e] = (u32)v0[e] | ((u32)v1[e] << 16);
        }
        #pragma unroll
        for (int e = 0; e < 8; ++e)
            *(u32*)&ldsT[(c0 + e) * 36 + kpair * 2] = pk[e];
        __syncthreads();

        short8 a[4];
        #pragma unroll
        for (int mt = 0; mt < 4; ++mt) {
            int row = mblk + wm + mt * 16 + l15;
            a[mt] = *(const short8*)(Wm + (size_t)row * K + k0 + qa * 8);
        }
        #pragma unroll
        for (int nt = 0; nt < 4; ++nt) {
            int c = wn + nt * 16 + l15;
            union { ushort4_t h[2]; short8 v; } bu;
            bu.h[0] = *(const ushort4_t*)&ldsT[c * 36 + qa * 8];
            bu.h[1] = *(const ushort4_t*)&ldsT[c * 36 + qa * 8 + 4];
            short8 b = bu.v;
            #pragma unroll
            for (int mt = 0; mt < 4; ++mt)
                acc[mt][nt] = __builtin_amdgcn_mfma_f32_16x16x32_bf16(a[mt], b, acc[mt][nt], 0, 0, 0);
        }
    }

    // epilogue: C/D layout col=lane&15, row=(lane>>4)*4+reg
    const int r4 = qa * 4;
    #pragma unroll
    for (int nt = 0; nt < 4; ++nt) {
        int colhw = hw0 + wn + nt * 16 + l15;
        if (colhw >= HW) continue;
        #pragma unroll
        for (int mt = 0; mt < 4; ++mt) {
            int mbase = mblk + wm + mt * 16 + r4;
            #pragma unroll
            for (int r = 0; r < 4; ++r) {
                int m = mbase + r;
                float v = acc[mt][nt][r] + bias[m];
                if (RELU) v = fmaxf(v, 0.f);
                size_t idx = ((size_t)n * ch_stride + ch_off + m) * HW + colhw;
                if (OUT_F32) ((float*)Out)[idx] = v;
                else         ((u16*)Out)[idx]  = f2b(v);
            }
        }
    }
}

// ---------------- kernel 4: both depthwise branches ----------------
// o1 = dwconv5x5(f, kern1(g)), o2 = dwconv3x3_dil2(f, kern2(g)); block per (n,cm)
__global__ __launch_bounds__(256) void dw_kernel(
    const u16* __restrict__ f, const float* __restrict__ g,
    const float* __restrict__ wk,  const float* __restrict__ bk,
    const float* __restrict__ wck, const float* __restrict__ bck,
    const float* __restrict__ wk2, const float* __restrict__ bk2,
    const float* __restrict__ wck2,const float* __restrict__ bck2,
    u16* __restrict__ o1, u16* __restrict__ o2)
{
    const int ncm = blockIdx.x;
    __shared__ float fpl[HW];
    __shared__ float kc1[25], kc2[9];

    const size_t base = (size_t)ncm * HW;
    const u32* fp = (const u32*)(f + base);
    for (int i = threadIdx.x; i < HW / 2; i += 256) {
        u32 v = fp[i];
        fpl[2 * i]     = b2f((u16)v);
        fpl[2 * i + 1] = b2f((u16)(v >> 16));
    }

    const float gv = g[ncm];
    if (threadIdx.x < 25) {
        int t = threadIdx.x;
        kc1[t] = (gv * wk[t] + bk[t]) * wck[0] + bck[0];
    } else if (threadIdx.x >= 32 && threadIdx.x < 41) {
        int t = threadIdx.x - 32;
        kc2[t] = (gv * wk2[t] + bk2[t]) * wck2[0] + bck2[0];
    }
    __syncthreads();

    u32* o1p = (u32*)(o1 + base);
    u32* o2p = (u32*)(o2 + base);
    for (int p2v = threadIdx.x; p2v < HW / 2; p2v += 256) {
        int px = p2v * 2;
        int h = px / HD, w = px - h * HD;   // w even, w+1 <= 55 (HD even)
        float a1[2] = {0.f, 0.f}, a2[2] = {0.f, 0.f};
        #pragma unroll
        for (int i = 0; i < 5; ++i) {
            int hh = h + i - 2; if (hh < 0 || hh >= HD) continue;
            const float* row = &fpl[hh * HD];
            #pragma unroll
            for (int j = 0; j < 5; ++j) {
                float kv = kc1[i * 5 + j];
                int w0 = w + j - 2;
                if (w0 >= 0 && w0 < HD) a1[0] += kv * row[w0];
                int w1 = w0 + 1;
                if (w1 >= 0 && w1 < HD) a1[1] += kv * row[w1];
            }
        }
        #pragma unroll
        for (int i = 0; i < 3; ++i) {
            int hh = h + (i - 1) * 2; if (hh < 0 || hh >= HD) continue;
            const float* row = &fpl[hh * HD];
            #pragma unroll
            for (int j = 0; j < 3; ++j) {
                float kv = kc2[i * 3 + j];
                int w0 = w + (j - 1) * 2;
                if (w0 >= 0 && w0 < HD) a2[0] += kv * row[w0];
                int w1 = w0 + 1;
                if (w1 >= 0 && w1 < HD) a2[1] += kv * row[w1];
            }
        }
        o1p[p2v] = (u32)f2b(a1[0]) | ((u32)f2b(a1[1]) << 16);
        o2p[p2v] = (u32)f2b(a2[0]) | ((u32)f2b(a2[1]) << 16);
    }
}

extern "C" void kernel_launch(void* const* d_in, const int* in_sizes, int n_in,
                              void* d_out, int out_size, void* d_ws, size_t ws_size,
                              hipStream_t stream) {
    const float* x     = (const float*)d_in[0];
    const float* Wconv = (const float*)d_in[1];
    const float* bconv = (const float*)d_in[2];
    const float* wk    = (const float*)d_in[3];
    const float* bk    = (const float*)d_in[4];
    const float* wck   = (const float*)d_in[5];
    const float* bck   = (const float*)d_in[6];
    const float* wk2   = (const float*)d_in[7];
    const float* bk2   = (const float*)d_in[8];
    const float* wck2  = (const float*)d_in[9];
    const float* bck2  = (const float*)d_in[10];
    const float* Wfuse = (const float*)d_in[11];
    const float* bfuse = (const float*)d_in[12];
    float* out = (float*)d_out;

    // workspace layout (all regions fully rewritten every call)
    float* xm  = (float*)d_ws;                // NB*CIN f32 (zeroed by init)
    float* g   = xm + NB * CIN;               // NB*CM f32
    u16*   Wcb = (u16*)(g + NB * CM);         // CM*CIN bf16
    u16*   Wfb = Wcb + CM * CIN;              // P2*CM bf16
    u16*   f   = Wfb + P2 * CM;               // NB*CM*HW bf16
    u16*   o1  = f  + (size_t)NB * CM * HW;   // NB*CM*HW bf16
    u16*   o2  = o1 + (size_t)NB * CM * HW;   // NB*CM*HW bf16

    {
        int tot = CM * CIN + P2 * CM + NB * CIN;
        init_kernel<<<dim3((tot + 255) / 256), 256, 0, stream>>>(Wconv, Wfuse, Wcb, Wfb, xm);
    }
    // f = relu(W_conv @ x) : M=128, K=512 ; also accumulates sum_hw(x) into xm
    gemm_kernel<1,0,1,1,0><<<dim3(25, 1, NB), 256, 0, stream>>>(
        x, nullptr, Wcb, bconv, f, xm, CIN, CM);
    g_kernel<<<dim3(NB), 128, 0, stream>>>(Wconv, bconv, xm, g);
    dw_kernel<<<dim3(NB * CM), 256, 0, stream>>>(f, g, wk, bk, wck, bck,
                                                 wk2, bk2, wck2, bck2, o1, o2);
    // y1/y2 = W_fuse @ o1/o2 + b_fuse : M=256, K=128; branch from blockIdx.z&1
    gemm_kernel<0,1,0,0,1><<<dim3(25, 2, 2 * NB), 256, 0, stream>>>(
        o1, o2, Wfb, bfuse, out, nullptr, CM, 512);
}